// Round 9
// baseline (523.097 us; speedup 1.0000x reference)
//
#include <hip/hip_runtime.h>
#include <hip/hip_bf16.h>

// CausalDiscoveryModule: B=256, N=512, E=32, IN=512, K=10
// out[b,i,j] = gate_b * sigmoid(logit) on per-(b,i)-row top-10 of j, else 0
// logit = sum_e (c_b^2 * emb_i)[e] * emb_j[e]
//
// R13 resubmit (previous round was an infra failure: container died before
// compile/verify; no measurement happened).
//
// R13 (wave specialization, writer path fixed):
//  - R12 post-mortem: writers were the floor. Fence-serialized LDS-compose
//    phases gave ~1.6 TB/s writer throughput (262MB -> ~165us trailing tail;
//    matches 206us + hbm 16%). Compute was fine.
//  - R13 writers: fence-free fill+scatter in 4-row chunks: dense dwordx4
//    zero-fill (coalesced), s_waitcnt vmcnt(0), per-lane 10-dword scatter to
//    own row. Scatter lands ~700cy after fill -> lines still in L2, no RMW
//    amplification (R5's version scattered ~100us after fill, everything
//    evicted). No DS round-trips, pure pipelined VMEM: ~2.4us/tile/writer.
//  - Structure: 256 thr: waves 0-1 = R8's exact j-half while-loop scan
//    (merge/sigmoid/epilogue OFF the compute path), waves 2-3 = writers.
//    2 tiles/block, grid 1024 -> 8 blk/CU, 32 waves/CU, 16 compute waves/CU
//    (R8's proven regime). Writers overlap tile-0 stores with tile-1 scan;
//    only tile-1's ~20us tail exposed.
//  - Barriers in COMMON code (2 total); double-buffered lists; LDS 15.4KB,
//    no unions/aliasing anywhere.

#define NUM_VARS 512
#define EMBED_DIM 32
#define IN_DIM 512
#define BATCH 256

typedef float nf4 __attribute__((ext_vector_type(4)));
typedef float f2 __attribute__((ext_vector_type(2)));

// ---------------- K1: context MLP -> w = c^2 [256][32], gate [256] ----------
__global__ __launch_bounds__(256) void cdm_k1(
    const float* __restrict__ ctx, const float* __restrict__ W1,
    const float* __restrict__ b1, const float* __restrict__ W2,
    const float* __restrict__ b2, const float* __restrict__ Wg,
    const float* __restrict__ bg, float* __restrict__ wws,
    float* __restrict__ gws) {
  const int bb = blockIdx.x;
  const int t = threadIdx.x;
  __shared__ float xs[512];
  __shared__ float psum[32][9];   // +1 pad
  __shared__ float hs[32];
  __shared__ float cs[32];
  const float* x = ctx + (bb << 9);
  xs[t] = x[t];
  xs[t + 256] = x[t + 256];
  __syncthreads();
  {
    const int e = t >> 3, part = t & 7;
    const float* wrow = W1 + e * 512 + part * 64;
    const float* xp = xs + part * 64;
    float a = 0.f;
#pragma unroll
    for (int m = 0; m < 64; ++m) a = fmaf(wrow[m], xp[m], a);
    psum[e][part] = a;
  }
  __syncthreads();
  if (t < 32) {
    float a = 0.f;
#pragma unroll
    for (int p = 0; p < 8; ++p) a += psum[t][p];
    hs[t] = fmaxf(a + b1[t], 0.f);
  }
  __syncthreads();
  if (t < 32) {
    const float* wrow = W2 + (t << 5);
    float a = 0.f;
#pragma unroll
    for (int k = 0; k < 32; ++k) a = fmaf(wrow[k], hs[k], a);
    float c = a + b2[t];
    cs[t] = c;
    wws[(bb << 5) + t] = c * c;
  }
  __syncthreads();
  if (t == 0) {
    float a = 0.f;
#pragma unroll
    for (int k = 0; k < 32; ++k) a = fmaf(Wg[k], cs[k], a);
    float g = a + bg[0];
    gws[bb] = 1.f / (1.f + __expf(-g));
  }
}

// strict-> shift insert: equal values keep earlier-inserted (lower j) above
#define TOP10_INSERT(av, aj, v, jn)                           \
  do {                                                        \
    _Pragma("unroll") for (int k = 9; k >= 1; --k) {          \
      bool gk = (v) > av[k];                                  \
      bool gk1 = (v) > av[k - 1];                             \
      av[k] = gk ? (gk1 ? av[k - 1] : (v)) : av[k];           \
      aj[k] = gk ? (gk1 ? aj[k - 1] : (jn)) : aj[k];          \
    }                                                         \
    bool g0 = (v) > av[0];                                    \
    av[0] = g0 ? (v) : av[0];                                 \
    aj[0] = g0 ? (jn) : aj[0];                                \
  } while (0)

// R8's proven j-half scan: 64 iters of 4 dots + while-loop exact top-10.
__device__ __forceinline__ void scan_half(
    const float* __restrict__ emb, const float* __restrict__ wws,
    int r0, int lane, int jbase, float hv[10], int hj[10]) {
  const int b = r0 >> 9;
  const int i = (r0 + lane) & 511;
  f2 sv2[16];
  {
    const f2* wb = reinterpret_cast<const f2*>(wws + (b << 5));
    const f2* ei = reinterpret_cast<const f2*>(emb + (i << 5));
#pragma unroll
    for (int p = 0; p < 16; ++p) sv2[p] = wb[p] * ei[p];
  }
#pragma unroll
  for (int k = 0; k < 10; ++k) { hv[k] = -1e30f; hj[k] = 0; }

  const f2* eb = reinterpret_cast<const f2*>(emb);
  for (int t = 0; t < 64; ++t) {
    const int j0 = jbase + (t << 2);
    const f2* e0 = eb + ((j0 + 0) << 4);
    const f2* e1 = eb + ((j0 + 1) << 4);
    const f2* e2 = eb + ((j0 + 2) << 4);
    const f2* e3 = eb + ((j0 + 3) << 4);
    f2 c0 = {0.f, 0.f}, c1 = {0.f, 0.f}, c2 = {0.f, 0.f}, c3 = {0.f, 0.f};
#pragma unroll
    for (int p = 0; p < 16; ++p) {
      c0 += sv2[p] * e0[p];   // v_pk_fma_f32
      c1 += sv2[p] * e1[p];
      c2 += sv2[p] * e2[p];
      c3 += sv2[p] * e3[p];
    }
    float a0 = c0.x + c0.y, a1 = c1.x + c1.y;
    float a2 = c2.x + c2.y, a3 = c3.x + c3.y;

    const float thr = hv[9];
    int p0 = a0 > thr, p1 = a1 > thr, p2 = a2 > thr, p3 = a3 > thr;
    while (__any(p0 | p1 | p2 | p3)) {
      if (p0 | p1 | p2 | p3) {
        float v;
        int jn;
        if (p0) { v = a0; jn = j0; p0 = 0; }
        else if (p1) { v = a1; jn = j0 + 1; p1 = 0; }
        else if (p2) { v = a2; jn = j0 + 2; p2 = 0; }
        else { v = a3; jn = j0 + 3; p3 = 0; }
        TOP10_INSERT(hv, hj, v, jn);
      }
      const float nt = hv[9];
      p0 = p0 && (a0 > nt);
      p1 = p1 && (a1 > nt);
      p2 = p2 && (a2 > nt);
      p3 = p3 && (a3 > nt);
    }
  }
}

// Writer: merge 2 half-lists (low half first => exact jax tie order), then
// fill+scatter rows [32W, 32W+32) of the tile in 8 chunks of 4 rows.
__device__ __forceinline__ void write_tile(
    int tt, int W, int lane, int r0, float gateb,
    const float (*mvv)[2][10][64], const unsigned short (*mjj)[2][10][64],
    float* __restrict__ out) {
  // lane l merges block-row l
  float fv[10];
  int fj[10];
#pragma unroll
  for (int k = 0; k < 10; ++k) {
    fv[k] = mvv[tt][0][k][lane];
    fj[k] = (int)mjj[tt][0][k][lane];
  }
#pragma unroll
  for (int qk = 0; qk < 10; ++qk) {
    float v = mvv[tt][1][qk][lane];
    int jn = (int)mjj[tt][1][qk][lane];
    if (v > fv[9]) TOP10_INSERT(fv, fj, v, jn);
  }
  float oval[10];
#pragma unroll
  for (int k = 0; k < 10; ++k) oval[k] = gateb / (1.f + __expf(-fv[k]));

  const nf4 z4 = {0.f, 0.f, 0.f, 0.f};
  float* myrow = out + ((size_t)(r0 + lane) << 9);
  for (int c = 0; c < 8; ++c) {
    const int cr0 = (W << 5) | (c << 2);   // block-relative first row of chunk
    // dense zero-fill of 4 rows, fully coalesced dwordx4
#pragma unroll
    for (int s = 0; s < 4; ++s) {
      nf4* ob = reinterpret_cast<nf4*>(out + ((size_t)(r0 + cr0 + s) << 9));
      ob[lane] = z4;
      ob[lane + 64] = z4;
    }
    asm volatile("s_waitcnt vmcnt(0)" ::: "memory");
    // scatter while the lines are still in L2 (~700cy later, no RMW fetch)
    if ((lane >> 2) == ((W << 3) | c)) {
#pragma unroll
      for (int k = 0; k < 10; ++k) myrow[fj[k]] = oval[k];
    }
  }
}

// ---- K2: 4-wave block; waves 0-1 scan j-halves, waves 2-3 write ------------
__global__ __launch_bounds__(256, 8) void cdm_k2(
    const float* __restrict__ emb, const float* __restrict__ wws,
    const float* __restrict__ gws, float* __restrict__ out) {
  const int lane = threadIdx.x & 63;
  const int wv = threadIdx.x >> 6;   // 0-1 compute (j-half), 2-3 writer
  const int G = __builtin_amdgcn_readfirstlane(blockIdx.x);

  // double-buffered half-lists: [tile][half][k][lane]
  __shared__ float mvv[2][2][10][64];            // 10240 B, lane-minor
  __shared__ unsigned short mjj[2][2][10][64];   //  5120 B

  const int r0t0 = (G << 1) << 6;        // tile 0 first row
  const int r0t1 = ((G << 1) | 1) << 6;  // tile 1 first row
  const bool is_compute = (wv < 2);

  float hv[10];
  int hj[10];

  // ---- tile 0 scan (compute) ----
  if (is_compute) {
    const int jbase = __builtin_amdgcn_readfirstlane(wv << 8);
    scan_half(emb, wws, r0t0, lane, jbase, hv, hj);
#pragma unroll
    for (int k = 0; k < 10; ++k) {
      mvv[0][wv][k][lane] = hv[k];
      mjj[0][wv][k][lane] = (unsigned short)hj[k];
    }
  }
  __syncthreads();   // barrier 1: tile-0 lists published

  // ---- tile 1 scan (compute) || tile 0 write (writers) ----
  if (is_compute) {
    const int jbase = __builtin_amdgcn_readfirstlane(wv << 8);
    scan_half(emb, wws, r0t1, lane, jbase, hv, hj);
#pragma unroll
    for (int k = 0; k < 10; ++k) {
      mvv[1][wv][k][lane] = hv[k];
      mjj[1][wv][k][lane] = (unsigned short)hj[k];
    }
  } else {
    write_tile(0, wv - 2, lane, r0t0, gws[r0t0 >> 9], mvv, mjj, out);
  }
  __syncthreads();   // barrier 2: tile-1 lists published

  // ---- tile 1 write (writers); compute waves exit ----
  if (!is_compute) {
    write_tile(1, wv - 2, lane, r0t1, gws[r0t1 >> 9], mvv, mjj, out);
  }
}

extern "C" void kernel_launch(void* const* d_in, const int* in_sizes, int n_in,
                              void* d_out, int out_size, void* d_ws,
                              size_t ws_size, hipStream_t stream) {
  const float* ctx = (const float*)d_in[0];
  const float* emb = (const float*)d_in[1];
  const float* W1 = (const float*)d_in[2];
  const float* b1 = (const float*)d_in[3];
  const float* W2 = (const float*)d_in[4];
  const float* b2 = (const float*)d_in[5];
  const float* Wg = (const float*)d_in[6];
  const float* bg = (const float*)d_in[7];
  float* out = (float*)d_out;
  float* wws = (float*)d_ws;            // 256*32 floats: c^2
  float* gws = wws + BATCH * EMBED_DIM; // 256 floats: gate

  cdm_k1<<<BATCH, 256, 0, stream>>>(ctx, W1, b1, W2, b2, Wg, bg, wws, gws);
  cdm_k2<<<1024, 256, 0, stream>>>(emb, wws, gws, out);
}

// Round 11
// 504.902 us; speedup vs baseline: 1.0360x; 1.0360x over previous
//
#include <hip/hip_runtime.h>
#include <hip/hip_bf16.h>

// CausalDiscoveryModule: B=256, N=512, E=32, IN=512, K=10
// out[b,i,j] = gate_b * sigmoid(logit) on per-(b,i)-row top-10 of j, else 0
// logit = sum_e (c_b^2 * emb_i)[e] * emb_j[e]
//
// R15 = R14 with the two OOB bugs fixed (R14 core-dumped; device fault):
//  BUG1: A-frag row indexed emb without &511 mask (r0 up to 131008 -> 16MB
//        OOB reads). Fixed: row = (r0 + rt*16 + l15) & 511.
//  BUG2: slab loop ran s=0..7 (1024 cols); N=512 -> s=0..3. (Also made jb
//        read emb rows 512..1023: OOB.) Fixed: 4 slabs x 4 waves x 32 = 512.
//
// R14 rationale (unchanged, untested until now):
//  - fp32 VALU peak = 1 FMA/lane/cy => the R8/R9 scan was AT its f32
//    roofline (~150us). Only exit: MFMA.
//  - S[b] = (w_b*emb) @ emb^T via mfma_f32_16x16x32_bf16 with 3-way bf16
//    splitting (x=b0+b1+b2, 8 MFMA/tile, small terms first): logit error
//    ~1e-5 ~ fp32-reorder scale; values exact to ~1e-6 after sigmoid.
//  - Per block (64 rows, 4 waves): wave q owns cols {s*128+q*32..+32},
//    s=0..3. A-frags built once. Per slab: B-split + 64 MFMA + C->LDS
//    (wave-private [64][32] f32, XOR swizzle byte^=(row&7)<<4) + scan via
//    ds_read_b128 (4 cols per insert-iter, 32 iters/wave total).
//  - Cross-wave merge: LEX insert (v desc, j asc) = exact jax tie order for
//    interleaved col-ranges. ONE barrier total.
//  - Epilogue: R9's proven 8x2-row LDS row-compose; rowbuf overlays the
//    wave's OWN scores slab (wave-private -> fences only).

#define NUM_VARS 512
#define EMBED_DIM 32
#define IN_DIM 512
#define BATCH 256

typedef float nf4 __attribute__((ext_vector_type(4)));
using bf16x8 = __attribute__((ext_vector_type(8))) short;   // 8 bf16 (4 VGPR)
using f32x4 = __attribute__((ext_vector_type(4))) float;

// ---------------- K1: context MLP -> w = c^2 [256][32], gate [256] ----------
__global__ __launch_bounds__(256) void cdm_k1(
    const float* __restrict__ ctx, const float* __restrict__ W1,
    const float* __restrict__ b1, const float* __restrict__ W2,
    const float* __restrict__ b2, const float* __restrict__ Wg,
    const float* __restrict__ bg, float* __restrict__ wws,
    float* __restrict__ gws) {
  const int bb = blockIdx.x;
  const int t = threadIdx.x;
  __shared__ float xs[512];
  __shared__ float psum[32][9];   // +1 pad
  __shared__ float hs[32];
  __shared__ float cs[32];
  const float* x = ctx + (bb << 9);
  xs[t] = x[t];
  xs[t + 256] = x[t + 256];
  __syncthreads();
  {
    const int e = t >> 3, part = t & 7;
    const float* wrow = W1 + e * 512 + part * 64;
    const float* xp = xs + part * 64;
    float a = 0.f;
#pragma unroll
    for (int m = 0; m < 64; ++m) a = fmaf(wrow[m], xp[m], a);
    psum[e][part] = a;
  }
  __syncthreads();
  if (t < 32) {
    float a = 0.f;
#pragma unroll
    for (int p = 0; p < 8; ++p) a += psum[t][p];
    hs[t] = fmaxf(a + b1[t], 0.f);
  }
  __syncthreads();
  if (t < 32) {
    const float* wrow = W2 + (t << 5);
    float a = 0.f;
#pragma unroll
    for (int k = 0; k < 32; ++k) a = fmaf(wrow[k], hs[k], a);
    float c = a + b2[t];
    cs[t] = c;
    wws[(bb << 5) + t] = c * c;
  }
  __syncthreads();
  if (t == 0) {
    float a = 0.f;
#pragma unroll
    for (int k = 0; k < 32; ++k) a = fmaf(Wg[k], cs[k], a);
    float g = a + bg[0];
    gws[bb] = 1.f / (1.f + __expf(-g));
  }
}

// strict-> shift insert (scan path: ascending-j arrival => exact jax ties)
#define TOP10_INSERT(av, aj, v, jn)                           \
  do {                                                        \
    _Pragma("unroll") for (int k = 9; k >= 1; --k) {          \
      bool gk = (v) > av[k];                                  \
      bool gk1 = (v) > av[k - 1];                             \
      av[k] = gk ? (gk1 ? av[k - 1] : (v)) : av[k];           \
      aj[k] = gk ? (gk1 ? aj[k - 1] : (jn)) : aj[k];          \
    }                                                         \
    bool g0 = (v) > av[0];                                    \
    av[0] = g0 ? (v) : av[0];                                 \
    aj[0] = g0 ? (jn) : aj[0];                                \
  } while (0)

// lexicographic insert (value desc, index asc): order-independent jax ties
#define LEX10_INSERT(av, aj, v, jn)                                         \
  do {                                                                      \
    _Pragma("unroll") for (int k = 9; k >= 1; --k) {                        \
      bool gk = ((v) > av[k]) || ((v) == av[k] && (jn) < aj[k]);            \
      bool gk1 = ((v) > av[k - 1]) || ((v) == av[k - 1] && (jn) < aj[k - 1]); \
      av[k] = gk ? (gk1 ? av[k - 1] : (v)) : av[k];                         \
      aj[k] = gk ? (gk1 ? aj[k - 1] : (jn)) : aj[k];                        \
    }                                                                       \
    bool g0 = ((v) > av[0]) || ((v) == av[0] && (jn) < aj[0]);              \
    av[0] = g0 ? (v) : av[0];                                               \
    aj[0] = g0 ? (jn) : aj[0];                                              \
  } while (0)

__device__ __forceinline__ unsigned short f2bf(float v) {
  unsigned u = __float_as_uint(v);
  u += 0x7fffu + ((u >> 16) & 1u);   // RN-even (values are finite/normal)
  return (unsigned short)(u >> 16);
}
__device__ __forceinline__ float bf2f(unsigned short h) {
  return __uint_as_float(((unsigned)h) << 16);
}
// x[0..7] fp32 -> 3 bf16x8 terms, x ~= b0+b1+b2 (24-bit combined mantissa)
__device__ __forceinline__ void split3(const float* x, bf16x8& b0, bf16x8& b1,
                                       bf16x8& b2) {
#pragma unroll
  for (int e = 0; e < 8; ++e) {
    float v = x[e];
    unsigned short h0 = f2bf(v);
    float r1 = v - bf2f(h0);
    unsigned short h1 = f2bf(r1);
    float r2 = r1 - bf2f(h1);
    unsigned short h2 = f2bf(r2);
    b0[e] = (short)h0;
    b1[e] = (short)h1;
    b2[e] = (short)h2;
  }
}

#define MFMA(A, B, C) __builtin_amdgcn_mfma_f32_16x16x32_bf16((A), (B), (C), 0, 0, 0)

// ---- K2: 4 waves; MFMA scores -> LDS -> cheap scan -> lex merge -> write ---
__global__ __launch_bounds__(256) void cdm_k2(
    const float* __restrict__ emb, const float* __restrict__ wws,
    const float* __restrict__ gws, float* __restrict__ out) {
  const int lane = threadIdx.x & 63;
  const int q = threadIdx.x >> 6;
  const int G = __builtin_amdgcn_readfirstlane(blockIdx.x);
  const int r0 = G << 6;            // 64 rows, same b
  const int b = r0 >> 9;
  const int l15 = lane & 15;
  const int kb = lane >> 4;         // k-block 0..3
  const int k8 = kb << 3;           // k = k8..k8+7

  __shared__ __align__(16) float sscores[4][2048];  // per-wave [64][32] swz
  __shared__ float mvv[4][10][64];                  // lane-minor lists
  __shared__ unsigned short mjj[4][10][64];

  float* sw = sscores[q];

  // ---- A-frags (rows r0..r0+63 -> emb rows (..)&511), built once ----
  bf16x8 A0[4], A1[4], A2[4];
  {
    float wv[8];
    const nf4* wp = reinterpret_cast<const nf4*>(wws + (b << 5) + k8);
    nf4 w0 = wp[0], w1 = wp[1];
    wv[0] = w0.x; wv[1] = w0.y; wv[2] = w0.z; wv[3] = w0.w;
    wv[4] = w1.x; wv[5] = w1.y; wv[6] = w1.z; wv[7] = w1.w;
#pragma unroll
    for (int rt = 0; rt < 4; ++rt) {
      const int row = (r0 + (rt << 4) + l15) & 511;   // BUG1 FIX: mask to emb
      const nf4* xp = reinterpret_cast<const nf4*>(emb + (row << 5) + k8);
      nf4 x0 = xp[0], x1 = xp[1];
      float pp[8];
      pp[0] = wv[0] * x0.x; pp[1] = wv[1] * x0.y;
      pp[2] = wv[2] * x0.z; pp[3] = wv[3] * x0.w;
      pp[4] = wv[4] * x1.x; pp[5] = wv[5] * x1.y;
      pp[6] = wv[6] * x1.z; pp[7] = wv[7] * x1.w;
      split3(pp, A0[rt], A1[rt], A2[rt]);
    }
  }

  float hv[10];
  int hj[10];
#pragma unroll
  for (int k = 0; k < 10; ++k) { hv[k] = -1e30f; hj[k] = 0; }

  for (int s = 0; s < 4; ++s) {   // BUG2 FIX: 4 slabs (4x4x32 = 512 cols)
#pragma unroll
    for (int tloc = 0; tloc < 2; ++tloc) {
      // B-frag: col j = lane&15 of this col-tile, k-slice kb
      const int jb = (s << 7) + (q << 5) + (tloc << 4) + l15;   // < 512
      bf16x8 B0, B1, B2;
      {
        const nf4* xp = reinterpret_cast<const nf4*>(emb + (jb << 5) + k8);
        nf4 x0 = xp[0], x1 = xp[1];
        float xx[8];
        xx[0] = x0.x; xx[1] = x0.y; xx[2] = x0.z; xx[3] = x0.w;
        xx[4] = x1.x; xx[5] = x1.y; xx[6] = x1.z; xx[7] = x1.w;
        split3(xx, B0, B1, B2);
      }
#pragma unroll
      for (int rt = 0; rt < 4; ++rt) {
        f32x4 C = {0.f, 0.f, 0.f, 0.f};
        C = MFMA(A1[rt], B2, C);   // smallest terms first
        C = MFMA(A2[rt], B1, C);
        C = MFMA(A2[rt], B0, C);
        C = MFMA(A0[rt], B2, C);
        C = MFMA(A1[rt], B1, C);
        C = MFMA(A1[rt], B0, C);
        C = MFMA(A0[rt], B1, C);
        C = MFMA(A0[rt], B0, C);
        // C layout (m89-verified): col=lane&15, row=(lane>>4)*4+reg
        const int coll = (tloc << 4) + l15;
#pragma unroll
        for (int r = 0; r < 4; ++r) {
          const int rowl = (rt << 4) + (kb << 2) + r;
          const int byo = (rowl << 7) + (((coll << 2)) ^ ((rowl & 7) << 4));
          *reinterpret_cast<float*>(reinterpret_cast<char*>(sw) + byo) = C[r];
        }
      }
    }
    asm volatile("" ::: "memory");   // C-writes before scan reads (R6 lesson)

    // ---- scan this slab's 32 cols: lane = row, 8x ds_read_b128 ----
    for (int ci = 0; ci < 8; ++ci) {
      const int byr = (lane << 7) + ((ci << 4) ^ ((lane & 7) << 4));
      nf4 v = *reinterpret_cast<const nf4*>(
          reinterpret_cast<const char*>(sw) + byr);
      const int j0 = (s << 7) + (q << 5) + (ci << 2);
      float a0 = v.x, a1 = v.y, a2 = v.z, a3 = v.w;

      const float thr = hv[9];
      int p0 = a0 > thr, p1 = a1 > thr, p2 = a2 > thr, p3 = a3 > thr;
      while (__any(p0 | p1 | p2 | p3)) {
        if (p0 | p1 | p2 | p3) {
          float v2;
          int jn;
          if (p0) { v2 = a0; jn = j0; p0 = 0; }
          else if (p1) { v2 = a1; jn = j0 + 1; p1 = 0; }
          else if (p2) { v2 = a2; jn = j0 + 2; p2 = 0; }
          else { v2 = a3; jn = j0 + 3; p3 = 0; }
          TOP10_INSERT(hv, hj, v2, jn);
        }
        const float nt = hv[9];
        p0 = p0 && (a0 > nt);
        p1 = p1 && (a1 > nt);
        p2 = p2 && (a2 > nt);
        p3 = p3 && (a3 > nt);
      }
    }
    asm volatile("" ::: "memory");   // scan reads before next slab's writes
  }

  // ---- publish + lex merge (order-independent exact jax ties) ----
#pragma unroll
  for (int k = 0; k < 10; ++k) {
    mvv[q][k][lane] = hv[k];
    mjj[q][k][lane] = (unsigned short)hj[k];
  }
  __syncthreads();   // the only barrier

  float fv[10];
  int fj[10];
#pragma unroll
  for (int k = 0; k < 10; ++k) {
    fv[k] = mvv[0][k][lane];
    fj[k] = (int)mjj[0][k][lane];
  }
#pragma unroll
  for (int m = 1; m < 4; ++m) {
#pragma unroll
    for (int k = 0; k < 10; ++k) {
      float v = mvv[m][k][lane];
      int jn = (int)mjj[m][k][lane];
      LEX10_INSERT(fv, fj, v, jn);
    }
  }

  const float gateb = gws[b];
  float oval[10];
#pragma unroll
  for (int k = 0; k < 10; ++k) oval[k] = gateb / (1.f + __expf(-fv[k]));

  // ---- epilogue: R9's 8x2-row LDS compose; rowbuf = wave's own scores ----
  float* rbw = sw;                           // wave-private overlay, fence-ordered
  nf4* rbw4 = reinterpret_cast<nf4*>(rbw);   // 256 nf4 = [2][512] floats
  {
    const nf4 z4 = {0.f, 0.f, 0.f, 0.f};
#pragma unroll
    for (int sI = 0; sI < 4; ++sI) rbw4[(sI << 6) + lane] = z4;
  }
  asm volatile("" ::: "memory");

  for (int p = 0; p < 8; ++p) {
    const int rbase = (q << 4) | (p << 1);   // even block-row
    const bool own = (lane >> 1) == (rbase >> 1);
    const int slot = lane & 1;
    if (own) {
      float* dst = rbw + (slot << 9);
#pragma unroll
      for (int k = 0; k < 10; ++k) dst[fj[k]] = oval[k];
    }
    asm volatile("" ::: "memory");   // scatter before reads
#pragma unroll
    for (int sI = 0; sI < 2; ++sI) {
      nf4 lo = rbw4[(sI << 7) + lane];
      nf4 hi = rbw4[(sI << 7) + 64 + lane];
      nf4* ob = reinterpret_cast<nf4*>(out + ((size_t)(r0 + rbase + sI) << 9));
      ob[lane] = lo;
      ob[lane + 64] = hi;
    }
    asm volatile("" ::: "memory");   // reads before rezero
    if (own) {
      float* dst = rbw + (slot << 9);
#pragma unroll
      for (int k = 0; k < 10; ++k) dst[fj[k]] = 0.f;
    }
    asm volatile("" ::: "memory");
  }
}

extern "C" void kernel_launch(void* const* d_in, const int* in_sizes, int n_in,
                              void* d_out, int out_size, void* d_ws,
                              size_t ws_size, hipStream_t stream) {
  const float* ctx = (const float*)d_in[0];
  const float* emb = (const float*)d_in[1];
  const float* W1 = (const float*)d_in[2];
  const float* b1 = (const float*)d_in[3];
  const float* W2 = (const float*)d_in[4];
  const float* b2 = (const float*)d_in[5];
  const float* Wg = (const float*)d_in[6];
  const float* bg = (const float*)d_in[7];
  float* out = (float*)d_out;
  float* wws = (float*)d_ws;            // 256*32 floats: c^2
  float* gws = wws + BATCH * EMBED_DIM; // 256 floats: gate

  cdm_k1<<<BATCH, 256, 0, stream>>>(ctx, W1, b1, W2, b2, Wg, bg, wws, gws);
  cdm_k2<<<2048, 256, 0, stream>>>(emb, wws, gws, out);
}